// Round 4
// baseline (420.551 us; speedup 1.0000x reference)
//
#include <hip/hip_runtime.h>
#include <hip/hip_bf16.h>
#include <cstdint>

#define T_    4096
#define HID_  2048
#define DH    128
#define NQ_   16
#define NKV_  4
#define QKVW  3072   // 2048 Q + 512 K + 512 V

typedef __attribute__((ext_vector_type(8))) short bf16x8;
typedef __attribute__((ext_vector_type(4))) float f32x4;
typedef __attribute__((ext_vector_type(16))) float f32x16;
typedef __attribute__((ext_vector_type(4))) float f4;
typedef __attribute__((ext_vector_type(4))) short s4;

__device__ __forceinline__ short f2bf(float f) {
  union { float f; unsigned u; } x; x.f = f;
  unsigned r = x.u + 0x7fffu + ((x.u >> 16) & 1u);
  return (short)(r >> 16);
}
__device__ __forceinline__ float bf2f(short s) {
  return __uint_as_float(((unsigned)(unsigned short)s) << 16);
}
__device__ __forceinline__ unsigned pkbf2(float a, float b) {
  union { __hip_bfloat162 h; unsigned u; } c;
  c.h = __float22bfloat162_rn(make_float2(a, b));
  return c.u;
}

__device__ __forceinline__ void gload16(const void* g, void* l) {
  __builtin_amdgcn_global_load_lds(
      (const __attribute__((address_space(1))) unsigned*)g,
      (__attribute__((address_space(3))) unsigned*)l, 16, 0, 0);
}

#define MFMA16(a, b, c) __builtin_amdgcn_mfma_f32_16x16x32_bf16(a, b, c, 0, 0, 0)
#define MFMA32(a, b, c) __builtin_amdgcn_mfma_f32_32x32x16_bf16(a, b, c, 0, 0, 0)

#define Z16 {0.f,0.f,0.f,0.f,0.f,0.f,0.f,0.f,0.f,0.f,0.f,0.f,0.f,0.f,0.f,0.f}
#define SCL2 0.127517432f  // (1/sqrt(128)) * log2(e), folded into Q at RoPE

// ---------------- fp32 -> bf16 conversion ----------------
__global__ void cvtk(const float* __restrict__ s, short* __restrict__ d, int n4) {
  int i = blockIdx.x * blockDim.x + threadIdx.x;
  const int stride = gridDim.x * blockDim.x;
  for (; i < n4; i += stride) {
    f4 v = ((const f4*)s)[i];
    s4 o;
    o[0] = f2bf(v[0]); o[1] = f2bf(v[1]); o[2] = f2bf(v[2]); o[3] = f2bf(v[3]);
    ((s4*)d)[i] = o;
  }
}

// ---------------- GEMM: C = A (MxK) * B^T, B stored (N,K) row-major ----------------
template <int BF16OUT>
__global__ __launch_bounds__(256) void gemm_bt(const short* __restrict__ A,
                                               const short* __restrict__ B,
                                               void* __restrict__ Cp,
                                               int N, int K) {
  __shared__ short lA[128 * 32];
  __shared__ short lB[128 * 32];
  const int tid = threadIdx.x;
  const int lane = tid & 63;
  const int w = tid >> 6;
  const int wr = w >> 1, wc = w & 1;
  const int l15 = lane & 15, l4 = lane >> 4;
  f32x4 acc[4][4];
#pragma unroll
  for (int m = 0; m < 4; m++)
#pragma unroll
    for (int n = 0; n < 4; n++) acc[m][n] = f32x4{0.f, 0.f, 0.f, 0.f};

  const short* Ag = A + (size_t)blockIdx.x * 128 * K;
  const short* Bg = B + (size_t)blockIdx.y * 128 * K;

  for (int kt = 0; kt < K; kt += 32) {
#pragma unroll
    for (int i = 0; i < 2; ++i) {
      const int cb = i * 256 + w * 64;      // wave-uniform chunk base
      const int c = cb + lane;              // chunk of 8 bf16 (16B)
      const int row = c >> 2, eo = (c & 3) << 3;
      gload16(Ag + (size_t)row * K + kt + eo, &lA[cb * 8]);
      gload16(Bg + (size_t)row * K + kt + eo, &lB[cb * 8]);
    }
    __syncthreads();
    bf16x8 af[4], bfr[4];
#pragma unroll
    for (int m = 0; m < 4; m++)
      af[m] = *(const bf16x8*)&lA[(wr * 64 + m * 16 + l15) * 32 + l4 * 8];
#pragma unroll
    for (int n = 0; n < 4; n++)
      bfr[n] = *(const bf16x8*)&lB[(wc * 64 + n * 16 + l15) * 32 + l4 * 8];
#pragma unroll
    for (int m = 0; m < 4; m++)
#pragma unroll
      for (int n = 0; n < 4; n++)
        acc[m][n] = MFMA16(af[m], bfr[n], acc[m][n]);
    __syncthreads();
  }

  const int r0 = blockIdx.x * 128 + wr * 64;
  const int c0 = blockIdx.y * 128 + wc * 64;
#pragma unroll
  for (int m = 0; m < 4; m++)
#pragma unroll
    for (int n = 0; n < 4; n++)
#pragma unroll
      for (int r = 0; r < 4; r++) {
        const int row = r0 + m * 16 + l4 * 4 + r;
        const int col = c0 + n * 16 + l15;
        if (BF16OUT)
          ((short*)Cp)[(size_t)row * N + col] = f2bf(acc[m][n][r]);
        else
          ((float*)Cp)[(size_t)row * N + col] = acc[m][n][r];
      }
}

// ---------------- RoPE (in-place; Q heads additionally pre-scaled by SCL2) ----------------
__global__ void rope_k(short* __restrict__ qkv, const int* __restrict__ pos) {
  const int row = blockIdx.x;
  const int sub = threadIdx.x >> 6;  // 0..3
  const int d = threadIdx.x & 63;
  const int head = blockIdx.y * 4 + sub;  // 0..19 : 16 Q heads then 4 K heads
  const int col0 = (head < NQ_) ? head * DH : HID_ + (head - NQ_) * DH;
  const float scl = (head < NQ_) ? SCL2 : 1.0f;
  short* p = qkv + (size_t)row * QKVW + col0;
  const float fp = (float)pos[row];
  const float freq = fp * powf(10000.0f, -(float)d * (1.0f / 64.0f));
  const float sn = sinf(freq), cs = cosf(freq);
  const float x1 = bf2f(p[d]);
  const float x2 = bf2f(p[d + 64]);
  p[d] = f2bf((x1 * cs - x2 * sn) * scl);
  p[d + 64] = f2bf((x2 * cs + x1 * sn) * scl);
}

// ---------------- causal GQA flash attention (v4) ----------------
// 512 blocks x 256 threads: block = (kvh, head-group of 2, pairi). 4 waves =
// 2 heads x 2 KV-splits. 2 independent blocks/CU -> cross-block MFMA/VALU overlap.
// Paired q-blocks (i, 127-i): equal work. Swapped S^T = mfma(K, Q^T).
// Q pre-scaled by SCL2 in rope_k; scores already in log2 domain.

// prefetch 2 tiles (even kv0=j*128, odd +64) into 16 regs (256 threads)
#define PRE(j)                                                                      \
  {                                                                                 \
    const int kv0e = (j) * 128, kv0o = (j) * 128 + 64;                              \
    _Pragma("unroll") for (int i = 0; i < 4; i++) {                                 \
      const int idx = i * 256 + tid;                                                \
      const int row = idx >> 4, e = (idx & 15) << 3;                                \
      kre[i] = *(const bf16x8*)(kbase + (size_t)(kv0e + row) * QKVW + e);           \
      kro[i] = *(const bf16x8*)(kbase + (size_t)(kv0o + row) * QKVW + e);           \
    }                                                                               \
    _Pragma("unroll") for (int i = 0; i < 2; i++) {                                 \
      const int idx = i * 256 + tid;                                                \
      const int rp = idx >> 4, e = (idx & 15) << 3;                                 \
      vre[2 * i]     = *(const bf16x8*)(vbase + (size_t)(kv0e + 2 * rp) * QKVW + e);     \
      vre[2 * i + 1] = *(const bf16x8*)(vbase + (size_t)(kv0e + 2 * rp + 1) * QKVW + e); \
      vro[2 * i]     = *(const bf16x8*)(vbase + (size_t)(kv0o + 2 * rp) * QKVW + e);     \
      vro[2 * i + 1] = *(const bf16x8*)(vbase + (size_t)(kv0o + 2 * rp + 1) * QKVW + e); \
    }                                                                               \
  }

__global__ __launch_bounds__(256, 2) void attn_k(const short* __restrict__ qkv,
                                                 short* __restrict__ aout) {
  __shared__ __align__(16) char smem[66048];  // 64KB staging (reused as O-merge) + ml
  char* sKe = smem;                 // K even tile: [64 rows][256B], XOR-swizzled
  char* sKo = smem + 16384;
  char* sVe = smem + 32768;         // V^T even: [128 d][128B], XOR-swizzled
  char* sVo = smem + 49152;
  float* ml = (float*)(smem + 65536);  // [head2][sp][2][32]

  // XCD-chunked decode: xcd gets 64 contiguous work items (same kvh region)
  const int bid = blockIdx.x;
  const int gwi = (bid & 7) * 64 + (bid >> 3);  // bijective on 512
  const int kvh = gwi >> 7;
  const int r_ = gwi & 127;
  const int hg = r_ & 1;
  const int pairi = r_ >> 1;                    // 0..63
  const int tid = threadIdx.x, lane = tid & 63, w = tid >> 6;
  const int head2 = w & 1, sp = w >> 1;
  const int hi = lane >> 5, l31 = lane & 31;
  const int h = kvh * 4 + hg * 2 + head2;

  const short* kbase = qkv + HID_ + kvh * DH;
  const short* vbase = qkv + HID_ + NKV_ * DH + kvh * DH;
  const char* bK = sp ? sKo : sKe;
  const char* bV = sp ? sVo : sVe;

  for (int hf = 0; hf < 2; ++hf) {
    const int qb = hf ? (127 - pairi) : pairi;
    const int qrow0 = qb * 32;
    const int ntiles = qb / 2 + 1;
    const int nsuper = (ntiles + 1) >> 1;
    const int myq = qrow0 + l31;

    bf16x8 qf[8];
    {
      const short* qp = qkv + (size_t)myq * QKVW + h * DH + hi * 8;
#pragma unroll
      for (int c = 0; c < 8; c++) qf[c] = *(const bf16x8*)(qp + c * 16);
    }
    f32x16 o[4] = {Z16, Z16, Z16, Z16};
    float m = -3e38f, l = 0.f;

    bf16x8 kre[4], kro[4], vre[4], vro[4];
    PRE(0)

    for (int j = 0; j < nsuper; ++j) {
      __syncthreads();  // prev buffers consumed (and prev half's O-merge done)
      // ---- write both staged tiles to LDS (swizzled) ----
#pragma unroll
      for (int i = 0; i < 4; i++) {
        const int idx = i * 256 + tid;
        const int row = idx >> 4, e16 = (idx & 15) << 4;
        const int swz = (((row >> 3) ^ row) & 7) << 4;
        *(bf16x8*)(sKe + row * 256 + (e16 ^ swz)) = kre[i];
        *(bf16x8*)(sKo + row * 256 + (e16 ^ swz)) = kro[i];
      }
#pragma unroll
      for (int i = 0; i < 2; i++) {
        const int idx = i * 256 + tid;
        const int rp = idx >> 4, e = (idx & 15) << 3;
#pragma unroll
        for (int jj = 0; jj < 8; jj++) {
          const int d = e + jj;
          const int swz = (((d >> 3) ^ d) & 7) << 4;
          const unsigned pe = ((unsigned)(unsigned short)vre[2 * i][jj]) |
                              (((unsigned)(unsigned short)vre[2 * i + 1][jj]) << 16);
          const unsigned po = ((unsigned)(unsigned short)vro[2 * i][jj]) |
                              (((unsigned)(unsigned short)vro[2 * i + 1][jj]) << 16);
          *(unsigned*)(sVe + d * 128 + ((rp * 4) ^ swz)) = pe;
          *(unsigned*)(sVo + d * 128 + ((rp * 4) ^ swz)) = po;
        }
      }
      __syncthreads();
      if (j + 1 < nsuper) PRE(j + 1)

      const int t = 2 * j + sp;
      if (t < ntiles) {
        const int kv0 = t * 64;
        // ---- S^T = K Q^T : two 32x32 tiles over kv rows (log2 domain) ----
        f32x16 s0 = Z16, s1 = Z16;
        const int sw0 = (((l31 >> 3) ^ l31) & 7) << 4;
        const int r1 = 32 + l31;
        const int sw1 = (((r1 >> 3) ^ r1) & 7) << 4;
#pragma unroll
        for (int c = 0; c < 8; c++) {
          const int co = c * 32 + hi * 16;
          const bf16x8 k0 = *(const bf16x8*)(bK + l31 * 256 + (co ^ sw0));
          const bf16x8 k1 = *(const bf16x8*)(bK + r1 * 256 + (co ^ sw1));
          s0 = MFMA32(k0, qf[c], s0);
          s1 = MFMA32(k1, qf[c], s1);
        }
        // ---- in-register online softmax ----
        float sv0[16], sv1[16];
        if (t == ntiles - 1) {
#pragma unroll
          for (int r = 0; r < 16; r++) {
            const int kk = (r & 3) + 8 * (r >> 2) + 4 * hi;
            sv0[r] = (kv0 + kk <= myq) ? s0[r] : -1e30f;
            sv1[r] = (kv0 + 32 + kk <= myq) ? s1[r] : -1e30f;
          }
        } else {
#pragma unroll
          for (int r = 0; r < 16; r++) {
            sv0[r] = s0[r];
            sv1[r] = s1[r];
          }
        }
        float mx[8];
#pragma unroll
        for (int r = 0; r < 8; r++)
          mx[r] = fmaxf(fmaxf(sv0[r], sv0[r + 8]), fmaxf(sv1[r], sv1[r + 8]));
#pragma unroll
        for (int st = 4; st > 0; st >>= 1)
#pragma unroll
          for (int r = 0; r < 4; r++)
            if (r < st) mx[r] = fmaxf(mx[r], mx[r + st]);
        float pm = fmaxf(mx[0], __shfl_xor(mx[0], 32));
        if (__any(pm > m + 11.5f)) {  // defer-max (T13)
          const float mn = fmaxf(m, pm);
          const float al = exp2f(m - mn);
          m = mn;
          l *= al;
#pragma unroll
          for (int r = 0; r < 16; r++) {
            const float ar = __shfl(al, (r & 3) + 8 * (r >> 2) + 4 * hi);
#pragma unroll
            for (int dt = 0; dt < 4; dt++) o[dt][r] *= ar;
          }
        }
        float pv0[16], pv1[16];
#pragma unroll
        for (int r = 0; r < 16; r++) {
          pv0[r] = exp2f(sv0[r] - m);
          pv1[r] = exp2f(sv1[r] - m);
        }
        float sum[8];
#pragma unroll
        for (int r = 0; r < 8; r++)
          sum[r] = (pv0[r] + pv0[r + 8]) + (pv1[r] + pv1[r + 8]);
#pragma unroll
        for (int st = 4; st > 0; st >>= 1)
#pragma unroll
          for (int r = 0; r < 4; r++)
            if (r < st) sum[r] = sum[r] + sum[r + st];
        l += sum[0] + __shfl_xor(sum[0], 32);

        // ---- P -> bf16 A-frags (cvt_pk + half-exchange), PV ----
        unsigned W0[8], W1[8];
#pragma unroll
        for (int i = 0; i < 8; i++) {
          W0[i] = pkbf2(pv0[2 * i], pv0[2 * i + 1]);
          W1[i] = pkbf2(pv1[2 * i], pv1[2 * i + 1]);
        }
#pragma unroll
        for (int kt = 0; kt < 2; kt++) {
#pragma unroll
          for (int hc = 0; hc < 2; hc++) {
            const int base = hc * 4;
            const unsigned a = kt ? W1[base] : W0[base];
            const unsigned c2 = kt ? W1[base + 1] : W0[base + 1];
            const unsigned b = kt ? W1[base + 2] : W0[base + 2];
            const unsigned d2 = kt ? W1[base + 3] : W0[base + 3];
            const unsigned as = __shfl_xor(a, 32);
            const unsigned cs = __shfl_xor(c2, 32);
            const unsigned bs = __shfl_xor(b, 32);
            const unsigned ds = __shfl_xor(d2, 32);
            union { unsigned u[4]; bf16x8 v; } fr;
            fr.u[0] = hi ? bs : a;
            fr.u[1] = hi ? ds : c2;
            fr.u[2] = hi ? b : as;
            fr.u[3] = hi ? d2 : cs;
            const int ko = kt * 64 + hc * 32 + hi * 16;
#pragma unroll
            for (int dt = 0; dt < 4; dt++) {
              const int row = dt * 32 + l31;
              const int swz = (((row >> 3) ^ row) & 7) << 4;
              const bf16x8 vf = *(const bf16x8*)(bV + row * 128 + (ko ^ swz));
              o[dt] = MFMA32(fr.v, vf, o[dt]);
            }
          }
        }
      }
    }

    // ---- merge the two KV-splits of each head, write out ----
    if (lane < 32) {
      ml[((head2 * 2 + sp) * 2) * 32 + lane] = m;
      ml[((head2 * 2 + sp) * 2 + 1) * 32 + lane] = l;
    }
    __syncthreads();
    const float mo = ml[((head2 * 2 + (1 - sp)) * 2) * 32 + l31];
    const float lo = ml[((head2 * 2 + (1 - sp)) * 2 + 1) * 32 + l31];
    const float M = fmaxf(m, mo);
    const float aown = exp2f(m - M);
    const float ltot = l * aown + lo * exp2f(mo - M);
#pragma unroll
    for (int r = 0; r < 16; r++) {
      const float ar = __shfl(aown, (r & 3) + 8 * (r >> 2) + 4 * hi);
#pragma unroll
      for (int dt = 0; dt < 4; dt++) o[dt][r] *= ar;
    }
    float* Ob = (float*)smem + head2 * 4096;  // [32 q][128 d]
    if (sp == 1) {
#pragma unroll
      for (int r = 0; r < 16; r++) {
        const int q = (r & 3) + 8 * (r >> 2) + 4 * hi;
#pragma unroll
        for (int dt = 0; dt < 4; dt++) Ob[q * 128 + dt * 32 + l31] = o[dt][r];
      }
    }
    __syncthreads();
    if (sp == 0) {
      const float ri = 1.0f / ltot;
#pragma unroll
      for (int r = 0; r < 16; r++) {
        const float rr = __shfl(ri, (r & 3) + 8 * (r >> 2) + 4 * hi);
        const int q = (r & 3) + 8 * (r >> 2) + 4 * hi;
#pragma unroll
        for (int dt = 0; dt < 4; dt++) {
          const float val = (o[dt][r] + Ob[q * 128 + dt * 32 + l31]) * rr;
          aout[(size_t)(qrow0 + q) * HID_ + h * DH + dt * 32 + l31] = f2bf(val);
        }
      }
    }
  }
}

extern "C" void kernel_launch(void* const* d_in, const int* in_sizes, int n_in,
                              void* d_out, int out_size, void* d_ws, size_t ws_size,
                              hipStream_t stream) {
  const float* hs = (const float*)d_in[0];
  const float* wq = (const float*)d_in[1];
  const float* wk = (const float*)d_in[2];
  const float* wv = (const float*)d_in[3];
  const float* wo = (const float*)d_in[4];
  const int* pos = (const int*)d_in[5];
  float* out = (float*)d_out;

  const size_t SZ_HS = (size_t)T_ * HID_;
  const size_t SZ_WQ = (size_t)HID_ * HID_;
  const size_t SZ_WK = (size_t)(NKV_ * DH) * HID_;
  const size_t SZ_W1 = (size_t)QKVW * HID_;
  const size_t SZ_QKV = (size_t)T_ * QKVW;

  short* hs_bf = (short*)d_ws;
  short* w1_bf = hs_bf + SZ_HS;
  short* wo_bf = w1_bf + SZ_W1;
  short* qkv = wo_bf + SZ_WQ;
  short* attn = qkv + SZ_QKV;

  cvtk<<<1024, 256, 0, stream>>>(hs, hs_bf, (int)(SZ_HS / 4));
  cvtk<<<1024, 256, 0, stream>>>(wq, w1_bf, (int)(SZ_WQ / 4));
  cvtk<<<256, 256, 0, stream>>>(wk, w1_bf + SZ_WQ, (int)(SZ_WK / 4));
  cvtk<<<256, 256, 0, stream>>>(wv, w1_bf + SZ_WQ + SZ_WK, (int)(SZ_WK / 4));
  cvtk<<<1024, 256, 0, stream>>>(wo, wo_bf, (int)(SZ_WQ / 4));

  // QKV projection: (4096 x 2048) * (3072 x 2048)^T -> qkv bf16
  gemm_bt<1><<<dim3(T_ / 128, QKVW / 128), 256, 0, stream>>>(hs_bf, w1_bf, qkv, QKVW, HID_);

  // RoPE on Q (16 heads, pre-scaled) + K (4 heads), in place
  rope_k<<<dim3(T_, 5), 256, 0, stream>>>(qkv, pos);

  // causal GQA flash attention -> attn bf16 (T, 2048)
  attn_k<<<dim3(512), 256, 0, stream>>>(qkv, attn);

  // output projection: (4096 x 2048) * (2048 x 2048)^T -> fp32 out
  gemm_bt<0><<<dim3(T_ / 128, HID_ / 128), 256, 0, stream>>>(attn, wo_bf, out, HID_, HID_);
}

// Round 5
// 336.602 us; speedup vs baseline: 1.2494x; 1.2494x over previous
//
#include <hip/hip_runtime.h>
#include <hip/hip_bf16.h>
#include <cstdint>

#define T_    4096
#define HID_  2048
#define DH    128
#define NQ_   16
#define NKV_  4
#define QKVW  3072   // 2048 Q + 512 K + 512 V

typedef __attribute__((ext_vector_type(8))) short bf16x8;
typedef __attribute__((ext_vector_type(4))) float f32x4;
typedef __attribute__((ext_vector_type(16))) float f32x16;
typedef __attribute__((ext_vector_type(4))) float f4;
typedef __attribute__((ext_vector_type(4))) short s4;

__device__ __forceinline__ short f2bf(float f) {
  union { float f; unsigned u; } x; x.f = f;
  unsigned r = x.u + 0x7fffu + ((x.u >> 16) & 1u);
  return (short)(r >> 16);
}
__device__ __forceinline__ float bf2f(short s) {
  return __uint_as_float(((unsigned)(unsigned short)s) << 16);
}
__device__ __forceinline__ unsigned pkbf2(float a, float b) {
  union { __hip_bfloat162 h; unsigned u; } c;
  c.h = __float22bfloat162_rn(make_float2(a, b));
  return c.u;
}

__device__ __forceinline__ void gload16(const void* g, void* l) {
  __builtin_amdgcn_global_load_lds(
      (const __attribute__((address_space(1))) unsigned*)g,
      (__attribute__((address_space(3))) unsigned*)l, 16, 0, 0);
}

#define MFMA16(a, b, c) __builtin_amdgcn_mfma_f32_16x16x32_bf16(a, b, c, 0, 0, 0)
#define MFMA32(a, b, c) __builtin_amdgcn_mfma_f32_32x32x16_bf16(a, b, c, 0, 0, 0)

#define Z16 {0.f,0.f,0.f,0.f,0.f,0.f,0.f,0.f,0.f,0.f,0.f,0.f,0.f,0.f,0.f,0.f}
#define SCL2 0.127517432f  // (1/sqrt(128)) * log2(e), folded into Q at RoPE

// ---------------- fp32 -> bf16 conversion ----------------
__global__ void cvtk(const float* __restrict__ s, short* __restrict__ d, int n4) {
  int i = blockIdx.x * blockDim.x + threadIdx.x;
  const int stride = gridDim.x * blockDim.x;
  for (; i < n4; i += stride) {
    f4 v = ((const f4*)s)[i];
    s4 o;
    o[0] = f2bf(v[0]); o[1] = f2bf(v[1]); o[2] = f2bf(v[2]); o[3] = f2bf(v[3]);
    ((s4*)d)[i] = o;
  }
}

// ---------------- GEMM: C = A (MxK) * B^T, B stored (N,K) row-major ----------------
template <int BF16OUT>
__global__ __launch_bounds__(256) void gemm_bt(const short* __restrict__ A,
                                               const short* __restrict__ B,
                                               void* __restrict__ Cp,
                                               int N, int K) {
  __shared__ short lA[128 * 32];
  __shared__ short lB[128 * 32];
  const int tid = threadIdx.x;
  const int lane = tid & 63;
  const int w = tid >> 6;
  const int wr = w >> 1, wc = w & 1;
  const int l15 = lane & 15, l4 = lane >> 4;
  f32x4 acc[4][4];
#pragma unroll
  for (int m = 0; m < 4; m++)
#pragma unroll
    for (int n = 0; n < 4; n++) acc[m][n] = f32x4{0.f, 0.f, 0.f, 0.f};

  const short* Ag = A + (size_t)blockIdx.x * 128 * K;
  const short* Bg = B + (size_t)blockIdx.y * 128 * K;

  for (int kt = 0; kt < K; kt += 32) {
#pragma unroll
    for (int i = 0; i < 2; ++i) {
      const int cb = i * 256 + w * 64;      // wave-uniform chunk base
      const int c = cb + lane;              // chunk of 8 bf16 (16B)
      const int row = c >> 2, eo = (c & 3) << 3;
      gload16(Ag + (size_t)row * K + kt + eo, &lA[cb * 8]);
      gload16(Bg + (size_t)row * K + kt + eo, &lB[cb * 8]);
    }
    __syncthreads();
    bf16x8 af[4], bfr[4];
#pragma unroll
    for (int m = 0; m < 4; m++)
      af[m] = *(const bf16x8*)&lA[(wr * 64 + m * 16 + l15) * 32 + l4 * 8];
#pragma unroll
    for (int n = 0; n < 4; n++)
      bfr[n] = *(const bf16x8*)&lB[(wc * 64 + n * 16 + l15) * 32 + l4 * 8];
#pragma unroll
    for (int m = 0; m < 4; m++)
#pragma unroll
      for (int n = 0; n < 4; n++)
        acc[m][n] = MFMA16(af[m], bfr[n], acc[m][n]);
    __syncthreads();
  }

  const int r0 = blockIdx.x * 128 + wr * 64;
  const int c0 = blockIdx.y * 128 + wc * 64;
#pragma unroll
  for (int m = 0; m < 4; m++)
#pragma unroll
    for (int n = 0; n < 4; n++)
#pragma unroll
      for (int r = 0; r < 4; r++) {
        const int row = r0 + m * 16 + l4 * 4 + r;
        const int col = c0 + n * 16 + l15;
        if (BF16OUT)
          ((short*)Cp)[(size_t)row * N + col] = f2bf(acc[m][n][r]);
        else
          ((float*)Cp)[(size_t)row * N + col] = acc[m][n][r];
      }
}

// ---------------- RoPE (in-place; Q heads additionally pre-scaled by SCL2) ----------------
__global__ void rope_k(short* __restrict__ qkv, const int* __restrict__ pos) {
  const int row = blockIdx.x;
  const int sub = threadIdx.x >> 6;  // 0..3
  const int d = threadIdx.x & 63;
  const int head = blockIdx.y * 4 + sub;  // 0..19 : 16 Q heads then 4 K heads
  const int col0 = (head < NQ_) ? head * DH : HID_ + (head - NQ_) * DH;
  const float scl = (head < NQ_) ? SCL2 : 1.0f;
  short* p = qkv + (size_t)row * QKVW + col0;
  const float fp = (float)pos[row];
  const float freq = fp * powf(10000.0f, -(float)d * (1.0f / 64.0f));
  const float sn = sinf(freq), cs = cosf(freq);
  const float x1 = bf2f(p[d]);
  const float x2 = bf2f(p[d + 64]);
  p[d] = f2bf((x1 * cs - x2 * sn) * scl);
  p[d + 64] = f2bf((x2 * cs + x1 * sn) * scl);
}

// ---------------- causal GQA flash attention (v5) ----------------
// 256 blocks x 512 threads. 8 waves = 4 heads x 2 KV-splits share staged KV
// (v3 structure, 175us) + LDS DOUBLE BUFFER: one barrier per supertile, the
// LDS write of tile j+1 overlaps compute of tile j. Q pre-scaled (log2 domain).
// Paired q-blocks (i, 127-i): equal work.

// prefetch supertile j (even kv0=j*128, odd +64) into 8 regs (512 threads)
#define PRE(j)                                                                      \
  {                                                                                 \
    const int kv0e = (j) * 128, kv0o = (j) * 128 + 64;                              \
    _Pragma("unroll") for (int i = 0; i < 2; i++) {                                 \
      const int idx = i * 512 + tid;                                                \
      const int row = idx >> 4, e = (idx & 15) << 3;                                \
      kre[i] = *(const bf16x8*)(kbase + (size_t)(kv0e + row) * QKVW + e);           \
      kro[i] = *(const bf16x8*)(kbase + (size_t)(kv0o + row) * QKVW + e);           \
    }                                                                               \
    {                                                                               \
      const int rp = tid >> 4, e = (tid & 15) << 3;                                 \
      vre[0] = *(const bf16x8*)(vbase + (size_t)(kv0e + 2 * rp) * QKVW + e);        \
      vre[1] = *(const bf16x8*)(vbase + (size_t)(kv0e + 2 * rp + 1) * QKVW + e);    \
      vro[0] = *(const bf16x8*)(vbase + (size_t)(kv0o + 2 * rp) * QKVW + e);        \
      vro[1] = *(const bf16x8*)(vbase + (size_t)(kv0o + 2 * rp + 1) * QKVW + e);    \
    }                                                                               \
  }

// write staged regs into buffer at bufp (swizzled)
#define WRITEBUF(bufp)                                                          \
  {                                                                             \
    char* sKe_ = (bufp);                                                        \
    char* sKo_ = (bufp) + 16384;                                                \
    char* sVe_ = (bufp) + 32768;                                                \
    char* sVo_ = (bufp) + 49152;                                                \
    _Pragma("unroll") for (int i = 0; i < 2; i++) {                             \
      const int idx = i * 512 + tid;                                            \
      const int row = idx >> 4, e16 = (idx & 15) << 4;                          \
      const int swz = (((row >> 3) ^ row) & 7) << 4;                            \
      *(bf16x8*)(sKe_ + row * 256 + (e16 ^ swz)) = kre[i];                      \
      *(bf16x8*)(sKo_ + row * 256 + (e16 ^ swz)) = kro[i];                      \
    }                                                                           \
    {                                                                           \
      const int rp = tid >> 4, e = (tid & 15) << 3;                             \
      _Pragma("unroll") for (int jj = 0; jj < 8; jj++) {                        \
        const int d = e + jj;                                                   \
        const int swz = (((d >> 3) ^ d) & 7) << 4;                              \
        const unsigned pe = ((unsigned)(unsigned short)vre[0][jj]) |            \
                            (((unsigned)(unsigned short)vre[1][jj]) << 16);     \
        const unsigned po = ((unsigned)(unsigned short)vro[0][jj]) |            \
                            (((unsigned)(unsigned short)vro[1][jj]) << 16);     \
        *(unsigned*)(sVe_ + d * 128 + ((rp * 4) ^ swz)) = pe;                   \
        *(unsigned*)(sVo_ + d * 128 + ((rp * 4) ^ swz)) = po;                   \
      }                                                                         \
    }                                                                           \
  }

__global__ __launch_bounds__(512) void attn_k(const short* __restrict__ qkv,
                                              short* __restrict__ aout) {
  // two 64KB staging buffers (double-buffer) + 2KB m/l exchange
  __shared__ __align__(16) char smem[133120];
  float* ml = (float*)(smem + 131072);  // [head][sp][2][32]

  const int lin = blockIdx.x;
  const int rl = (lin & 7) * 32 + (lin >> 3);  // XCD-chunked remap (bijective on 256)
  const int kvh = rl >> 6;
  const int pairi = rl & 63;
  const int tid = threadIdx.x, lane = tid & 63, w = tid >> 6;
  const int head = w & 3, sp = w >> 2;
  const int hi = lane >> 5, l31 = lane & 31;
  const int h = kvh * 4 + head;

  const short* kbase = qkv + HID_ + kvh * DH;
  const short* vbase = qkv + HID_ + NKV_ * DH + kvh * DH;
  const int spoff = sp ? 16384 : 0;

  for (int hf = 0; hf < 2; ++hf) {
    const int qb = hf ? (127 - pairi) : pairi;
    const int qrow0 = qb * 32;
    const int ntiles = qb / 2 + 1;
    const int nsuper = (ntiles + 1) >> 1;
    const int myq = qrow0 + l31;

    bf16x8 qf[8];
    {
      const short* qp = qkv + (size_t)myq * QKVW + h * DH + hi * 8;
#pragma unroll
      for (int c = 0; c < 8; c++) qf[c] = *(const bf16x8*)(qp + c * 16);
    }
    f32x16 o[4] = {Z16, Z16, Z16, Z16};
    float m = -3e38f, l = 0.f;

    bf16x8 kre[2], kro[2], vre[2], vro[2];
    // prologue: fill buf0, prefetch supertile 1
    PRE(0)
    WRITEBUF(smem)
    if (nsuper > 1) PRE(1)

    for (int j = 0; j < nsuper; ++j) {
      __syncthreads();  // publishes buf[j&1]; prev compute on buf[(j+1)&1] done
      if (j + 1 < nsuper) {
        WRITEBUF(smem + ((j + 1) & 1) * 65536)  // overlaps compute below
        if (j + 2 < nsuper) PRE(j + 2)
      }
      const char* base = smem + (j & 1) * 65536;
      const char* bK = base + spoff;
      const char* bV = base + 32768 + spoff;

      const int t = 2 * j + sp;
      if (t < ntiles) {
        const int kv0 = t * 64;
        // ---- S^T = K Q^T : two 32x32 tiles over kv rows (log2 domain) ----
        f32x16 s0 = Z16, s1 = Z16;
        const int sw0 = (((l31 >> 3) ^ l31) & 7) << 4;
        const int r1 = 32 + l31;
        const int sw1 = (((r1 >> 3) ^ r1) & 7) << 4;
#pragma unroll
        for (int c = 0; c < 8; c++) {
          const int co = c * 32 + hi * 16;
          const bf16x8 k0 = *(const bf16x8*)(bK + l31 * 256 + (co ^ sw0));
          const bf16x8 k1 = *(const bf16x8*)(bK + r1 * 256 + (co ^ sw1));
          s0 = MFMA32(k0, qf[c], s0);
          s1 = MFMA32(k1, qf[c], s1);
        }
        // ---- in-register online softmax ----
        float sv0[16], sv1[16];
        if (t == ntiles - 1) {
#pragma unroll
          for (int r = 0; r < 16; r++) {
            const int kk = (r & 3) + 8 * (r >> 2) + 4 * hi;
            sv0[r] = (kv0 + kk <= myq) ? s0[r] : -1e30f;
            sv1[r] = (kv0 + 32 + kk <= myq) ? s1[r] : -1e30f;
          }
        } else {
#pragma unroll
          for (int r = 0; r < 16; r++) {
            sv0[r] = s0[r];
            sv1[r] = s1[r];
          }
        }
        float mx[8];
#pragma unroll
        for (int r = 0; r < 8; r++)
          mx[r] = fmaxf(fmaxf(sv0[r], sv0[r + 8]), fmaxf(sv1[r], sv1[r + 8]));
#pragma unroll
        for (int st = 4; st > 0; st >>= 1)
#pragma unroll
          for (int r = 0; r < 4; r++)
            if (r < st) mx[r] = fmaxf(mx[r], mx[r + st]);
        float pm = fmaxf(mx[0], __shfl_xor(mx[0], 32));
        if (__any(pm > m + 11.5f)) {  // defer-max (T13)
          const float mn = fmaxf(m, pm);
          const float al = exp2f(m - mn);
          m = mn;
          l *= al;
#pragma unroll
          for (int r = 0; r < 16; r++) {
            const float ar = __shfl(al, (r & 3) + 8 * (r >> 2) + 4 * hi);
#pragma unroll
            for (int dt = 0; dt < 4; dt++) o[dt][r] *= ar;
          }
        }
        float pv0[16], pv1[16];
#pragma unroll
        for (int r = 0; r < 16; r++) {
          pv0[r] = exp2f(sv0[r] - m);
          pv1[r] = exp2f(sv1[r] - m);
        }
        float sum[8];
#pragma unroll
        for (int r = 0; r < 8; r++)
          sum[r] = (pv0[r] + pv0[r + 8]) + (pv1[r] + pv1[r + 8]);
#pragma unroll
        for (int st = 4; st > 0; st >>= 1)
#pragma unroll
          for (int r = 0; r < 4; r++)
            if (r < st) sum[r] = sum[r] + sum[r + st];
        l += sum[0] + __shfl_xor(sum[0], 32);

        // ---- P -> bf16 A-frags (cvt_pk + half-exchange), PV ----
        unsigned W0[8], W1[8];
#pragma unroll
        for (int i = 0; i < 8; i++) {
          W0[i] = pkbf2(pv0[2 * i], pv0[2 * i + 1]);
          W1[i] = pkbf2(pv1[2 * i], pv1[2 * i + 1]);
        }
#pragma unroll
        for (int kt = 0; kt < 2; kt++) {
#pragma unroll
          for (int hc = 0; hc < 2; hc++) {
            const int base2 = hc * 4;
            const unsigned a = kt ? W1[base2] : W0[base2];
            const unsigned c2 = kt ? W1[base2 + 1] : W0[base2 + 1];
            const unsigned b = kt ? W1[base2 + 2] : W0[base2 + 2];
            const unsigned d2 = kt ? W1[base2 + 3] : W0[base2 + 3];
            const unsigned as = __shfl_xor(a, 32);
            const unsigned cs = __shfl_xor(c2, 32);
            const unsigned bs = __shfl_xor(b, 32);
            const unsigned ds = __shfl_xor(d2, 32);
            union { unsigned u[4]; bf16x8 v; } fr;
            fr.u[0] = hi ? bs : a;
            fr.u[1] = hi ? ds : c2;
            fr.u[2] = hi ? b : as;
            fr.u[3] = hi ? d2 : cs;
            const int ko = kt * 64 + hc * 32 + hi * 16;
#pragma unroll
            for (int dt = 0; dt < 4; dt++) {
              const int row = dt * 32 + l31;
              const int swz = (((row >> 3) ^ row) & 7) << 4;
              const bf16x8 vf = *(const bf16x8*)(bV + row * 128 + (ko ^ swz));
              o[dt] = MFMA32(fr.v, vf, o[dt]);
            }
          }
        }
      }
    }

    // ---- merge the two KV-splits of each head, write out ----
    if (lane < 32) {
      ml[((head * 2 + sp) * 2) * 32 + lane] = m;
      ml[((head * 2 + sp) * 2 + 1) * 32 + lane] = l;
    }
    __syncthreads();  // also: all compute reads of staging buffers done
    const float mo = ml[((head * 2 + (1 - sp)) * 2) * 32 + l31];
    const float lo = ml[((head * 2 + (1 - sp)) * 2 + 1) * 32 + l31];
    const float M = fmaxf(m, mo);
    const float aown = exp2f(m - M);
    const float ltot = l * aown + lo * exp2f(mo - M);
#pragma unroll
    for (int r = 0; r < 16; r++) {
      const float ar = __shfl(aown, (r & 3) + 8 * (r >> 2) + 4 * hi);
#pragma unroll
      for (int dt = 0; dt < 4; dt++) o[dt][r] *= ar;
    }
    float* Ob = (float*)smem + head * 4096;  // [32 q][128 d], reuses buf0
    if (sp == 1) {
#pragma unroll
      for (int r = 0; r < 16; r++) {
        const int q = (r & 3) + 8 * (r >> 2) + 4 * hi;
#pragma unroll
        for (int dt = 0; dt < 4; dt++) Ob[q * 128 + dt * 32 + l31] = o[dt][r];
      }
    }
    __syncthreads();
    if (sp == 0) {
      const float ri = 1.0f / ltot;
#pragma unroll
      for (int r = 0; r < 16; r++) {
        const float rr = __shfl(ri, (r & 3) + 8 * (r >> 2) + 4 * hi);
        const int q = (r & 3) + 8 * (r >> 2) + 4 * hi;
#pragma unroll
        for (int dt = 0; dt < 4; dt++) {
          const float val = (o[dt][r] + Ob[q * 128 + dt * 32 + l31]) * rr;
          aout[(size_t)(qrow0 + q) * HID_ + h * DH + dt * 32 + l31] = f2bf(val);
        }
      }
    }
    __syncthreads();  // Ob reads done before next hf's prologue WRITEBUF
  }
}

extern "C" void kernel_launch(void* const* d_in, const int* in_sizes, int n_in,
                              void* d_out, int out_size, void* d_ws, size_t ws_size,
                              hipStream_t stream) {
  const float* hs = (const float*)d_in[0];
  const float* wq = (const float*)d_in[1];
  const float* wk = (const float*)d_in[2];
  const float* wv = (const float*)d_in[3];
  const float* wo = (const float*)d_in[4];
  const int* pos = (const int*)d_in[5];
  float* out = (float*)d_out;

  const size_t SZ_HS = (size_t)T_ * HID_;
  const size_t SZ_WQ = (size_t)HID_ * HID_;
  const size_t SZ_WK = (size_t)(NKV_ * DH) * HID_;
  const size_t SZ_W1 = (size_t)QKVW * HID_;
  const size_t SZ_QKV = (size_t)T_ * QKVW;

  short* hs_bf = (short*)d_ws;
  short* w1_bf = hs_bf + SZ_HS;
  short* wo_bf = w1_bf + SZ_W1;
  short* qkv = wo_bf + SZ_WQ;
  short* attn = qkv + SZ_QKV;

  cvtk<<<1024, 256, 0, stream>>>(hs, hs_bf, (int)(SZ_HS / 4));
  cvtk<<<1024, 256, 0, stream>>>(wq, w1_bf, (int)(SZ_WQ / 4));
  cvtk<<<256, 256, 0, stream>>>(wk, w1_bf + SZ_WQ, (int)(SZ_WK / 4));
  cvtk<<<256, 256, 0, stream>>>(wv, w1_bf + SZ_WQ + SZ_WK, (int)(SZ_WK / 4));
  cvtk<<<1024, 256, 0, stream>>>(wo, wo_bf, (int)(SZ_WQ / 4));

  // QKV projection: (4096 x 2048) * (3072 x 2048)^T -> qkv bf16
  gemm_bt<1><<<dim3(T_ / 128, QKVW / 128), 256, 0, stream>>>(hs_bf, w1_bf, qkv, QKVW, HID_);

  // RoPE on Q (16 heads, pre-scaled) + K (4 heads), in place
  rope_k<<<dim3(T_, 5), 256, 0, stream>>>(qkv, pos);

  // causal GQA flash attention -> attn bf16 (T, 2048)
  attn_k<<<dim3(256), 512, 0, stream>>>(qkv, attn);

  // output projection: (4096 x 2048) * (2048 x 2048)^T -> fp32 out
  gemm_bt<0><<<dim3(T_ / 128, HID_ / 128), 256, 0, stream>>>(attn, wo_bf, out, HID_, HID_);
}